// Round 1
// baseline (510.881 us; speedup 1.0000x reference)
//
#include <hip/hip_runtime.h>
#include <stdint.h>

// Problem constants (fixed by setup_inputs): B=2, C=80, A=1024, H=W=2048
#define BATCH 2
#define NCLS 80
#define NA 1024
#define IMG_W 2048.0f
#define IMG_H 2048.0f
#define NT 256
#define PER_T (NA / NT)  // 4

// monotone float -> uint mapping (ascending uint order == ascending float order)
__device__ __forceinline__ unsigned enc_f32(float f) {
  unsigned u = __float_as_uint(f);
  return (u & 0x80000000u) ? ~u : (u | 0x80000000u);
}

__global__ __launch_bounds__(NT) void nms_kernel(
    const float* __restrict__ cls_pred,   // (B, C, A)
    const float* __restrict__ reg_pred,   // (B, 4, A)
    const float* __restrict__ anchors,    // (A, 4)
    float* __restrict__ out)              // (B, C, A, 5)
{
#pragma clang fp contract(off)
  const int bc  = blockIdx.x;       // 0..159
  const int b   = bc / NCLS;
  const int tid = threadIdx.x;

  // LDS layout (48 KB), with phase-based reuse:
  //   [0,16K)   obox  (boxes in original order)      -> outbox (scatter phase)
  //   [16K,32K) sbox  (boxes in sorted order)
  //   [32K,40K) skey  (u64 sort keys)
  //   [40K,44K) sarea (areas, sorted order)          -> outsc  (scatter phase)
  //   [44K,48K) keepL (keep flags, sorted order)
  __shared__ __align__(16) unsigned char smem[49152];
  float4*             obox  = (float4*)(smem);
  float4*             sbox  = (float4*)(smem + 16384);
  unsigned long long* skey  = (unsigned long long*)(smem + 32768);
  float*              sarea = (float*)(smem + 40960);
  int*                keepL = (int*)(smem + 45056);

  // ---- Phase 1: decode + clip boxes, build sort keys --------------------
  const float* regb = reg_pred + (size_t)b * 4 * NA;
  const float* scb  = cls_pred + (size_t)bc * NA;
  for (int a = tid; a < NA; a += NT) {
    float4 an = ((const float4*)anchors)[a];
    float w  = an.z - an.x;
    float h  = an.w - an.y;
    float cx = an.x + 0.5f * w;
    float cy = an.y + 0.5f * h;
    float dx = regb[0 * NA + a] * 0.1f;
    float dy = regb[1 * NA + a] * 0.1f;
    float dw = regb[2 * NA + a] * 0.2f;
    float dh = regb[3 * NA + a] * 0.2f;
    float pcx = cx + dx * w;
    float pcy = cy + dy * h;
    float pw  = expf(dw) * w;
    float ph  = expf(dh) * h;
    float x1 = fmaxf(pcx - 0.5f * pw, 0.0f);
    float y1 = pcy - 0.5f * ph;
    x1 = fmaxf(x1, 0.0f);
    y1 = fmaxf(y1, 0.0f);
    float x2 = fminf(pcx + 0.5f * pw, IMG_W);
    float y2 = fminf(pcy + 0.5f * ph, IMG_H);
    obox[a] = make_float4(x1, y1, x2, y2);

    float s   = scb[a];
    float key = (s > 0.05f) ? -s : __int_as_float(0x7f800000);  // +inf if invalid
    skey[a] = ((unsigned long long)enc_f32(key) << 32) | (unsigned)a;
  }
  __syncthreads();

  // ---- Phase 2: bitonic sort ascending (stable: idx in low 32 bits) -----
  for (int k = 2; k <= NA; k <<= 1) {
    for (int j = k >> 1; j > 0; j >>= 1) {
      for (int m = tid; m < NA; m += NT) {
        int mx = m ^ j;
        if (mx > m) {
          unsigned long long va = skey[m];
          unsigned long long vb = skey[mx];
          bool up = ((m & k) == 0);
          // keys are unique (idx in low bits) so va != vb always
          if ((va > vb) == up) { skey[m] = vb; skey[mx] = va; }
        }
      }
      __syncthreads();
    }
  }

  // ---- Phase 3: gather boxes/areas/keep into sorted order ---------------
  float4 bj[PER_T];
  float  aj[PER_T];
  int    kj[PER_T];
#pragma unroll
  for (int m = 0; m < PER_T; ++m) {
    int r = tid + m * NT;
    unsigned long long kv = skey[r];
    int orig = (int)(unsigned)kv;
    float4 bx = obox[orig];
    sbox[r] = bx;
    float ar = (bx.z - bx.x) * (bx.w - bx.y);
    sarea[r] = ar;
    int kp = ((unsigned)(kv >> 32) != 0xFF800000u) ? 1 : 0;  // finite key?
    keepL[r] = kp;
    bj[m] = bx;
    aj[m] = ar;
    kj[m] = kp;
  }

  // ---- Phase 4: greedy NMS, sequential over sorted ranks ----------------
  for (int i = 0; i < NA; ++i) {
    __syncthreads();            // make prior iteration's keepL writes visible
    if (keepL[i] == 0) continue;  // uniform branch (same LDS word for all)
    float4 bi = sbox[i];        // LDS broadcast
    float  ai = sarea[i];
#pragma unroll
    for (int m = 0; m < PER_T; ++m) {
      int j = tid + m * NT;
      if (j > i && kj[m]) {
        float ix1 = fmaxf(bi.x, bj[m].x);
        float iy1 = fmaxf(bi.y, bj[m].y);
        float ix2 = fminf(bi.z, bj[m].z);
        float iy2 = fminf(bi.w, bj[m].w);
        float inter = fmaxf(ix2 - ix1, 0.0f) * fmaxf(iy2 - iy1, 0.0f);
        float un = fmaxf(ai + aj[m] - inter, 1e-9f);
        float iou = inter / un;   // exact IEEE div, same as reference
        if (iou > 0.5f) { kj[m] = 0; keepL[j] = 0; }
      }
    }
  }
  __syncthreads();  // all NMS reads of sarea/sbox done before overlay below

  // ---- Phase 5: scatter back to original anchor order (reuse LDS) -------
  float4* outbox = obox;   // overlay
  float*  outsc  = sarea;  // overlay
#pragma unroll
  for (int m = 0; m < PER_T; ++m) {
    int r = tid + m * NT;
    unsigned long long kv = skey[r];
    int orig = (int)(unsigned)kv;
    float  sc = 0.0f;
    float4 bx = make_float4(0.0f, 0.0f, 0.0f, 0.0f);
    if (kj[m]) {
      sc = -__uint_as_float(~(unsigned)(kv >> 32));  // decode score from key
      bx = sbox[r];
    }
    outsc[orig]  = sc;
    outbox[orig] = bx;
  }
  __syncthreads();

  // ---- Phase 6: coalesced store: out[bc, a, 0..4] = {score, x1,y1,x2,y2}
  float* ob = out + (size_t)bc * NA * 5;
  for (int a = tid; a < NA; a += NT) {
    float4 bx = outbox[a];
    float  sc = outsc[a];
    float* o = ob + (size_t)a * 5;
    o[0] = sc;
    o[1] = bx.x;
    o[2] = bx.y;
    o[3] = bx.z;
    o[4] = bx.w;
  }
}

extern "C" void kernel_launch(void* const* d_in, const int* in_sizes, int n_in,
                              void* d_out, int out_size, void* d_ws, size_t ws_size,
                              hipStream_t stream) {
  // setup_inputs order: image, cls_pred, reg_pred, anchors
  const float* cls = (const float*)d_in[1];
  const float* reg = (const float*)d_in[2];
  const float* anc = (const float*)d_in[3];
  float* out = (float*)d_out;
  nms_kernel<<<dim3(BATCH * NCLS), dim3(NT), 0, stream>>>(cls, reg, anc, out);
}

// Round 2
// 414.091 us; speedup vs baseline: 1.2337x; 1.2337x over previous
//
#include <hip/hip_runtime.h>
#include <stdint.h>

// Problem constants (fixed by setup_inputs): B=2, C=80, A=1024, H=W=2048
#define BATCH 2
#define NCLS 80
#define NP (BATCH * NCLS)   // 160 independent NMS problems
#define NA 1024
#define IMG_W 2048.0f
#define IMG_H 2048.0f
#define NT 256
#define PER_T (NA / NT)  // 4
#define NWORD (NA / 64)  // 16

// monotone float -> uint mapping (ascending uint order == ascending float order)
__device__ __forceinline__ unsigned enc_f32(float f) {
  unsigned u = __float_as_uint(f);
  return (u & 0x80000000u) ? ~u : (u | 0x80000000u);
}

// ---------------------------------------------------------------------------
// Kernel A: decode boxes, build stable sort keys, bitonic sort, emit
//   skeyG[p][r]  (u64: enc(-score or +inf)<<32 | orig_idx, ascending==score desc)
//   sboxG[p][r]  (float4 box in sorted order)
//   nvalidG[p]   (count of scores > 0.05)
// ---------------------------------------------------------------------------
__global__ __launch_bounds__(NT) void decode_sort_kernel(
    const float* __restrict__ cls_pred,   // (B, C, A)
    const float* __restrict__ reg_pred,   // (B, 4, A)
    const float* __restrict__ anchors,    // (A, 4)
    unsigned long long* __restrict__ skeyG,  // (NP, NA)
    float4* __restrict__ sboxG,              // (NP, NA)
    int* __restrict__ nvalidG)               // (NP)
{
#pragma clang fp contract(off)
  const int bc  = blockIdx.x;
  const int b   = bc / NCLS;
  const int tid = threadIdx.x;

  __shared__ __align__(16) float4 obox[NA];            // 16 KB
  __shared__ unsigned long long skey[NA];              // 8 KB
  __shared__ int cntS;

  if (tid == 0) cntS = 0;
  __syncthreads();

  const float* regb = reg_pred + (size_t)b * 4 * NA;
  const float* scb  = cls_pred + (size_t)bc * NA;
  int localcnt = 0;
  for (int a = tid; a < NA; a += NT) {
    float4 an = ((const float4*)anchors)[a];
    float w  = an.z - an.x;
    float h  = an.w - an.y;
    float cx = an.x + 0.5f * w;
    float cy = an.y + 0.5f * h;
    float dx = regb[0 * NA + a] * 0.1f;
    float dy = regb[1 * NA + a] * 0.1f;
    float dw = regb[2 * NA + a] * 0.2f;
    float dh = regb[3 * NA + a] * 0.2f;
    float pcx = cx + dx * w;
    float pcy = cy + dy * h;
    float pw  = expf(dw) * w;
    float ph  = expf(dh) * h;
    float x1 = fmaxf(pcx - 0.5f * pw, 0.0f);
    float y1 = pcy - 0.5f * ph;
    x1 = fmaxf(x1, 0.0f);
    y1 = fmaxf(y1, 0.0f);
    float x2 = fminf(pcx + 0.5f * pw, IMG_W);
    float y2 = fminf(pcy + 0.5f * ph, IMG_H);
    obox[a] = make_float4(x1, y1, x2, y2);

    float s    = scb[a];
    bool valid = (s > 0.05f);
    localcnt  += valid ? 1 : 0;
    float key  = valid ? -s : __int_as_float(0x7f800000);  // +inf if invalid
    skey[a] = ((unsigned long long)enc_f32(key) << 32) | (unsigned)a;
  }
  atomicAdd(&cntS, localcnt);
  __syncthreads();

  // stable bitonic sort ascending (unique keys: idx in low 32 bits)
  for (int k = 2; k <= NA; k <<= 1) {
    for (int j = k >> 1; j > 0; j >>= 1) {
      for (int m = tid; m < NA; m += NT) {
        int mx = m ^ j;
        if (mx > m) {
          unsigned long long va = skey[m];
          unsigned long long vb = skey[mx];
          bool up = ((m & k) == 0);
          if ((va > vb) == up) { skey[m] = vb; skey[mx] = va; }
        }
      }
      __syncthreads();
    }
  }

  // emit
  unsigned long long* pk = skeyG + (size_t)bc * NA;
  float4* pb = sboxG + (size_t)bc * NA;
#pragma unroll
  for (int m = 0; m < PER_T; ++m) {
    int r = tid + m * NT;
    unsigned long long kv = skey[r];
    int orig = (int)(unsigned)kv;
    pk[r] = kv;
    pb[r] = obox[orig];
  }
  if (tid == 0) nvalidG[bc] = cntS;
}

// ---------------------------------------------------------------------------
// Kernel B: suppression bitmask matrix.
//   masks[p][i][w] bit jj = (iou(sorted i, sorted j=w*64+jj) > 0.5) && (j > i)
//   Written for rows i < nvalid, words w >= i>>6. Fully parallel.
// ---------------------------------------------------------------------------
__global__ __launch_bounds__(NT) void mask_kernel(
    const float4* __restrict__ sboxG,
    const int* __restrict__ nvalidG,
    unsigned long long* __restrict__ masks)   // (NP, NA, NWORD)
{
#pragma clang fp contract(off)
  const int p   = blockIdx.y;
  const int ic  = blockIdx.x;          // 0..3  (i-chunk of 256 rows)
  const int tid = threadIdx.x;

  __shared__ __align__(16) float4 sb[NA];   // 16 KB
  __shared__ float sa[NA];                  // 4 KB

  const float4* pb = sboxG + (size_t)p * NA;
  for (int r = tid; r < NA; r += NT) {
    float4 bx = pb[r];
    sb[r] = bx;
    sa[r] = (bx.z - bx.x) * (bx.w - bx.y);
  }
  int nv = nvalidG[p];
  __syncthreads();

  const int i = ic * NT + tid;
  if (i >= nv) return;

  float4 bi = sb[i];
  float  ai = sa[i];
  unsigned long long* mrow = masks + ((size_t)p * NA + i) * NWORD;

  for (int w = (i >> 6); w < NWORD; ++w) {
    unsigned long long bits = 0ull;
    const int jbase = w * 64;
#pragma unroll 8
    for (int jj = 0; jj < 64; ++jj) {
      int j = jbase + jj;
      float4 bj = sb[j];
      float ix1 = fmaxf(bi.x, bj.x);
      float iy1 = fmaxf(bi.y, bj.y);
      float ix2 = fminf(bi.z, bj.z);
      float iy2 = fminf(bi.w, bj.w);
      float inter = fmaxf(ix2 - ix1, 0.0f) * fmaxf(iy2 - iy1, 0.0f);
      float un = fmaxf(ai + sa[j] - inter, 1e-9f);
      float iou = inter / un;              // exact IEEE div, matches reference
      if ((j > i) & (iou > 0.5f)) bits |= (1ull << jj);
    }
    mrow[w] = bits;
  }
}

// ---------------------------------------------------------------------------
// Kernel C: greedy scan over bitmask + output. One wave (64 thr) per problem.
// ---------------------------------------------------------------------------
__global__ __launch_bounds__(64) void scan_kernel(
    const unsigned long long* __restrict__ skeyG,
    const float4* __restrict__ sboxG,
    const unsigned long long* __restrict__ masks,
    const int* __restrict__ nvalidG,
    float* __restrict__ out)              // (NP, NA, 5)
{
  const int p    = blockIdx.x;
  const int lane = threadIdx.x;

  __shared__ unsigned long long diagS[64];
  __shared__ unsigned long long keptS[NWORD];
  __shared__ unsigned long long remS[NWORD];
  __shared__ __align__(16) float outAll[NA * 5];   // 20 KB

  const int nv = nvalidG[p];
  if (lane < NWORD) { remS[lane] = 0ull; keptS[lane] = 0ull; }
  __syncthreads();

  const unsigned long long* pm = masks + (size_t)p * NA * NWORD;
  const int nchunk = (nv + 63) >> 6;

  for (int c = 0; c < nchunk; ++c) {
    int row = c * 64 + lane;
    diagS[lane] = (row < nv) ? pm[(size_t)row * NWORD + c] : 0ull;
    __syncthreads();

    if (lane == 0) {
      unsigned long long S = remS[c];
      unsigned long long kept = 0ull;
      int kmax = nv - c * 64;
      if (kmax > 64) kmax = 64;
      for (int k = 0; k < kmax; ++k) {
        if (!((S >> k) & 1ull)) {
          kept |= (1ull << k);
          S |= diagS[k];
        }
      }
      keptS[c] = kept;
    }
    __syncthreads();

    // parallel OR of kept rows' masks into remove words w > c
    unsigned long long kept = keptS[c];
    int w = lane & 15, g = lane >> 4;
    unsigned long long acc = 0ull;
    if (w > c) {
      for (int kk = 0; kk < 16; ++kk) {
        int k = g * 16 + kk;
        if ((kept >> k) & 1ull)
          acc |= pm[(size_t)(c * 64 + k) * NWORD + w];
      }
    }
    acc |= __shfl_xor(acc, 16);
    acc |= __shfl_xor(acc, 32);
    if (lane < 16 && w > c) remS[w] |= acc;
    __syncthreads();
  }

  // stage output (original anchor order) in LDS
  const unsigned long long* pk = skeyG + (size_t)p * NA;
  const float4* pb = sboxG + (size_t)p * NA;
  for (int r = lane; r < NA; r += 64) {
    unsigned long long kv = pk[r];
    int orig = (int)(unsigned)kv;
    bool kp = (keptS[r >> 6] >> (r & 63)) & 1ull;
    float sc = 0.0f;
    float4 bx = make_float4(0.0f, 0.0f, 0.0f, 0.0f);
    if (kp) {
      sc = -__uint_as_float(~(unsigned)(kv >> 32));  // exact original score
      bx = pb[r];
    }
    float* oa = outAll + (size_t)orig * 5;
    oa[0] = sc; oa[1] = bx.x; oa[2] = bx.y; oa[3] = bx.z; oa[4] = bx.w;
  }
  __syncthreads();

  // coalesced store
  float4* og = (float4*)(out + (size_t)p * NA * 5);
  const float4* ol = (const float4*)outAll;
  for (int t = lane; t < (NA * 5) / 4; t += 64) og[t] = ol[t];
}

// ---------------------------------------------------------------------------
// Fallback: round-1 monolithic kernel (used only if ws_size is too small)
// ---------------------------------------------------------------------------
__global__ __launch_bounds__(NT) void nms_mono_kernel(
    const float* __restrict__ cls_pred,
    const float* __restrict__ reg_pred,
    const float* __restrict__ anchors,
    float* __restrict__ out)
{
#pragma clang fp contract(off)
  const int bc  = blockIdx.x;
  const int b   = bc / NCLS;
  const int tid = threadIdx.x;

  __shared__ __align__(16) unsigned char smem[49152];
  float4*             obox  = (float4*)(smem);
  float4*             sbox  = (float4*)(smem + 16384);
  unsigned long long* skey  = (unsigned long long*)(smem + 32768);
  float*              sarea = (float*)(smem + 40960);
  int*                keepL = (int*)(smem + 45056);

  const float* regb = reg_pred + (size_t)b * 4 * NA;
  const float* scb  = cls_pred + (size_t)bc * NA;
  for (int a = tid; a < NA; a += NT) {
    float4 an = ((const float4*)anchors)[a];
    float w  = an.z - an.x;
    float h  = an.w - an.y;
    float cx = an.x + 0.5f * w;
    float cy = an.y + 0.5f * h;
    float dx = regb[0 * NA + a] * 0.1f;
    float dy = regb[1 * NA + a] * 0.1f;
    float dw = regb[2 * NA + a] * 0.2f;
    float dh = regb[3 * NA + a] * 0.2f;
    float pcx = cx + dx * w;
    float pcy = cy + dy * h;
    float pw  = expf(dw) * w;
    float ph  = expf(dh) * h;
    float x1 = fmaxf(fmaxf(pcx - 0.5f * pw, 0.0f), 0.0f);
    float y1 = fmaxf(pcy - 0.5f * ph, 0.0f);
    float x2 = fminf(pcx + 0.5f * pw, IMG_W);
    float y2 = fminf(pcy + 0.5f * ph, IMG_H);
    obox[a] = make_float4(x1, y1, x2, y2);
    float s   = scb[a];
    float key = (s > 0.05f) ? -s : __int_as_float(0x7f800000);
    skey[a] = ((unsigned long long)enc_f32(key) << 32) | (unsigned)a;
  }
  __syncthreads();
  for (int k = 2; k <= NA; k <<= 1) {
    for (int j = k >> 1; j > 0; j >>= 1) {
      for (int m = tid; m < NA; m += NT) {
        int mx = m ^ j;
        if (mx > m) {
          unsigned long long va = skey[m];
          unsigned long long vb = skey[mx];
          bool up = ((m & k) == 0);
          if ((va > vb) == up) { skey[m] = vb; skey[mx] = va; }
        }
      }
      __syncthreads();
    }
  }
  float4 bj[PER_T]; float aj[PER_T]; int kj[PER_T];
#pragma unroll
  for (int m = 0; m < PER_T; ++m) {
    int r = tid + m * NT;
    unsigned long long kv = skey[r];
    int orig = (int)(unsigned)kv;
    float4 bx = obox[orig];
    sbox[r] = bx;
    float ar = (bx.z - bx.x) * (bx.w - bx.y);
    sarea[r] = ar;
    int kp = ((unsigned)(kv >> 32) != 0xFF800000u) ? 1 : 0;
    keepL[r] = kp;
    bj[m] = bx; aj[m] = ar; kj[m] = kp;
  }
  for (int i = 0; i < NA; ++i) {
    __syncthreads();
    if (keepL[i] == 0) continue;
    float4 bi = sbox[i];
    float  ai = sarea[i];
#pragma unroll
    for (int m = 0; m < PER_T; ++m) {
      int j = tid + m * NT;
      if (j > i && kj[m]) {
        float ix1 = fmaxf(bi.x, bj[m].x);
        float iy1 = fmaxf(bi.y, bj[m].y);
        float ix2 = fminf(bi.z, bj[m].z);
        float iy2 = fminf(bi.w, bj[m].w);
        float inter = fmaxf(ix2 - ix1, 0.0f) * fmaxf(iy2 - iy1, 0.0f);
        float un = fmaxf(ai + aj[m] - inter, 1e-9f);
        if (inter / un > 0.5f) { kj[m] = 0; keepL[j] = 0; }
      }
    }
  }
  __syncthreads();
  float4* outbox = obox;
  float*  outsc  = sarea;
#pragma unroll
  for (int m = 0; m < PER_T; ++m) {
    int r = tid + m * NT;
    unsigned long long kv = skey[r];
    int orig = (int)(unsigned)kv;
    float  sc = 0.0f;
    float4 bx = make_float4(0.0f, 0.0f, 0.0f, 0.0f);
    if (kj[m]) {
      sc = -__uint_as_float(~(unsigned)(kv >> 32));
      bx = sbox[r];
    }
    outsc[orig]  = sc;
    outbox[orig] = bx;
  }
  __syncthreads();
  float* ob = out + (size_t)bc * NA * 5;
  for (int a = tid; a < NA; a += NT) {
    float4 bx = outbox[a];
    float* o = ob + (size_t)a * 5;
    o[0] = outsc[a]; o[1] = bx.x; o[2] = bx.y; o[3] = bx.z; o[4] = bx.w;
  }
}

// ---------------------------------------------------------------------------
extern "C" void kernel_launch(void* const* d_in, const int* in_sizes, int n_in,
                              void* d_out, int out_size, void* d_ws, size_t ws_size,
                              hipStream_t stream) {
  const float* cls = (const float*)d_in[1];
  const float* reg = (const float*)d_in[2];
  const float* anc = (const float*)d_in[3];
  float* out = (float*)d_out;

  // workspace layout (all 256B-aligned)
  const size_t off_key  = 0;                                    // NP*NA*8
  const size_t off_box  = off_key + (size_t)NP * NA * 8;        // NP*NA*16
  const size_t off_mask = off_box + (size_t)NP * NA * 16;       // NP*NA*NWORD*8
  const size_t off_nv   = off_mask + (size_t)NP * NA * NWORD * 8;
  const size_t need     = off_nv + (size_t)NP * sizeof(int);

  if (ws_size < need) {
    // not enough scratch: monolithic fallback (correct, slower)
    nms_mono_kernel<<<dim3(NP), dim3(NT), 0, stream>>>(cls, reg, anc, out);
    return;
  }

  char* ws = (char*)d_ws;
  unsigned long long* skeyG = (unsigned long long*)(ws + off_key);
  float4*             sboxG = (float4*)(ws + off_box);
  unsigned long long* masks = (unsigned long long*)(ws + off_mask);
  int*                nvG   = (int*)(ws + off_nv);

  decode_sort_kernel<<<dim3(NP), dim3(NT), 0, stream>>>(cls, reg, anc, skeyG, sboxG, nvG);
  mask_kernel<<<dim3(4, NP), dim3(NT), 0, stream>>>(sboxG, nvG, masks);
  scan_kernel<<<dim3(NP), dim3(64), 0, stream>>>(skeyG, sboxG, masks, nvG, out);
}

// Round 3
// 327.614 us; speedup vs baseline: 1.5594x; 1.2640x over previous
//
#include <hip/hip_runtime.h>
#include <stdint.h>

// Problem constants (fixed by setup_inputs): B=2, C=80, A=1024, H=W=2048
#define BATCH 2
#define NCLS 80
#define NP (BATCH * NCLS)   // 160 independent NMS problems
#define NA 1024
#define NWORD 16            // NA/64
#define IMG_W 2048.0f
#define IMG_H 2048.0f
#define NT 1024             // fused kernel block size (16 waves)
#define NWAVE 16

// monotone float -> uint mapping (ascending uint order == ascending float order)
__device__ __forceinline__ unsigned enc_f32(float f) {
  unsigned u = __float_as_uint(f);
  return (u & 0x80000000u) ? ~u : (u | 0x80000000u);
}

// ---------------------------------------------------------------------------
// Fused kernel: one block per (batch,class) problem.
// Phases: decode -> bitonic sort -> suppression-mask matrix (global ws) ->
//         ballot-greedy scan -> staged coalesced output.
// ---------------------------------------------------------------------------
__global__ __launch_bounds__(NT) void nms_fused(
    const float* __restrict__ cls_pred,   // (B, C, A)
    const float* __restrict__ reg_pred,   // (B, 4, A)
    const float* __restrict__ anchors,    // (A, 4)
    unsigned long long* __restrict__ masksG,  // (NP, NA, NWORD) scratch
    float* __restrict__ out)              // (B, C, A, 5)
{
#pragma clang fp contract(off)
  const int p      = blockIdx.x;
  const int b      = p / NCLS;
  const int tid    = threadIdx.x;
  const int waveId = tid >> 6;
  const int lane   = tid & 63;

  // LDS layout (45.6 KB), phase-overlaid:
  //  [0,16384)      obox (orig order)        | outAll[0:4096]   (phase 6)
  //  [16384,20480)  sarea (sorted areas)     | outAll[4096:5120](phase 6)
  //  [20480,36864)  sbox (sorted boxes)
  //  [36864,45056)  skey (u64 sort keys)
  //  [45056,45568)  keptS[16], remS[16], cnt
  __shared__ __align__(16) unsigned char smem[45568];
  float4*             obox  = (float4*)(smem);
  float*              sarea = (float*)(smem + 16384);
  float*              outAll= (float*)(smem);            // overlay, phase 6
  float4*             sbox  = (float4*)(smem + 20480);
  unsigned long long* skey  = (unsigned long long*)(smem + 36864);
  unsigned long long* keptS = (unsigned long long*)(smem + 45056);
  unsigned long long* remS  = (unsigned long long*)(smem + 45056 + 128);
  int*                cntS  = (int*)(smem + 45056 + 256);

  if (tid == 0) *cntS = 0;
  if (tid < NWORD) { keptS[tid] = 0ull; remS[tid] = 0ull; }
  __syncthreads();

  // ---- Phase 1: decode + clip + sort keys (1 anchor / thread) -----------
  {
    const float* regb = reg_pred + (size_t)b * 4 * NA;
    const float* scb  = cls_pred + (size_t)p * NA;
    const int a = tid;
    float4 an = ((const float4*)anchors)[a];
    float w  = an.z - an.x;
    float h  = an.w - an.y;
    float cx = an.x + 0.5f * w;
    float cy = an.y + 0.5f * h;
    float dx = regb[0 * NA + a] * 0.1f;
    float dy = regb[1 * NA + a] * 0.1f;
    float dw = regb[2 * NA + a] * 0.2f;
    float dh = regb[3 * NA + a] * 0.2f;
    float pcx = cx + dx * w;
    float pcy = cy + dy * h;
    float pw  = expf(dw) * w;
    float ph  = expf(dh) * h;
    float x1 = fmaxf(pcx - 0.5f * pw, 0.0f);
    float y1 = pcy - 0.5f * ph;
    x1 = fmaxf(x1, 0.0f);
    y1 = fmaxf(y1, 0.0f);
    float x2 = fminf(pcx + 0.5f * pw, IMG_W);
    float y2 = fminf(pcy + 0.5f * ph, IMG_H);
    obox[a] = make_float4(x1, y1, x2, y2);

    float s    = scb[a];
    bool valid = (s > 0.05f);
    if (valid) atomicAdd(cntS, 1);
    float key  = valid ? -s : __int_as_float(0x7f800000);  // +inf if invalid
    skey[a] = ((unsigned long long)enc_f32(key) << 32) | (unsigned)a;
  }
  __syncthreads();

  const int nv = *cntS;                 // stable from here on
  const int nchunk = (nv + 63) >> 6;

  // ---- Phase 2: stable bitonic sort ascending (idx in low 32 bits) ------
  for (int k = 2; k <= NA; k <<= 1) {
    for (int j = k >> 1; j > 0; j >>= 1) {
      const int m  = tid;
      const int mx = m ^ j;
      if (mx > m) {
        unsigned long long va = skey[m];
        unsigned long long vb = skey[mx];
        bool up = ((m & k) == 0);
        if ((va > vb) == up) { skey[m] = vb; skey[mx] = va; }
      }
      __syncthreads();
    }
  }

  // ---- Phase 3: gather into sorted order --------------------------------
  {
    const int r = tid;
    unsigned long long kv = skey[r];
    int orig = (int)(unsigned)kv;
    float4 bx = obox[orig];
    sbox[r]  = bx;
    sarea[r] = (bx.z - bx.x) * (bx.w - bx.y);
  }
  __syncthreads();

  // ---- Phase 4: suppression bitmask matrix ------------------------------
  // Task (w, g): word w (cols j=w*64..w*64+63), row-blocks rb=4g..4g+3 (rb<=w).
  // Each lane caches 4 row-boxes in registers; one LDS broadcast of box j
  // feeds 4 IOUs.  Exact-rounding predicate replaces the IEEE divide:
  //   RN(inter/un) > 0.5  <=>  (2*inter - un) > un * 2^-24   (see analysis)
  {
    int t = 0;
    for (int w = 0; w < nchunk; ++w) {
      for (int g = 0; 4 * g <= w; ++g, ++t) {
        if ((t % NWAVE) != waveId) continue;
        float4 bi[4]; float ai[4]; unsigned long long bits[4];
        bool act[4]; int irow[4];
#pragma unroll
        for (int k = 0; k < 4; ++k) {
          int rb = 4 * g + k;
          irow[k] = rb * 64 + lane;
          act[k]  = (rb <= w) && (irow[k] < nv);
          bits[k] = 0ull;
          if (act[k]) { bi[k] = sbox[irow[k]]; ai[k] = sarea[irow[k]]; }
        }
        const int jbase = w * 64;
        for (int jj = 0; jj < 64; ++jj) {
          float4 bj = sbox[jbase + jj];   // wave-broadcast
          float  aj = sarea[jbase + jj];
#pragma unroll
          for (int k = 0; k < 4; ++k) {
            if (act[k]) {
              float ix1 = fmaxf(bi[k].x, bj.x);
              float iy1 = fmaxf(bi[k].y, bj.y);
              float ix2 = fminf(bi[k].z, bj.z);
              float iy2 = fminf(bi[k].w, bj.w);
              float inter = fmaxf(ix2 - ix1, 0.0f) * fmaxf(iy2 - iy1, 0.0f);
              float un = fmaxf((ai[k] + aj) - inter, 1e-9f);
              bool sup = ((inter + inter) - un) > un * 5.9604644775390625e-8f;
              bits[k] |= sup ? (1ull << jj) : 0ull;
            }
          }
        }
#pragma unroll
        for (int k = 0; k < 4; ++k) {
          if (act[k]) {
            int rb = 4 * g + k;
            unsigned long long bv = bits[k];
            if (rb == w)   // diagonal word: only j > i counts
              bv &= (lane == 63) ? 0ull : ((~0ull) << (lane + 1));
            masksG[((size_t)p * NA + irow[k]) * NWORD + w] = bv;
          }
        }
      }
    }
  }
  __syncthreads();

  // ---- Phase 5: ballot-greedy scan --------------------------------------
  {
    const unsigned long long* pm = masksG + (size_t)p * NA * NWORD;
    for (int c = 0; c < nchunk; ++c) {
      if (waveId == 0) {
        int kmax = nv - c * 64; if (kmax > 64) kmax = 64;
        unsigned long long diag = 0ull;
        if (lane < kmax) diag = pm[(size_t)(c * 64 + lane) * NWORD + c];
        unsigned long long S = remS[c];
        bool alive = (lane < kmax) && !((S >> lane) & 1ull);
        unsigned long long kept = 0ull;
        while (true) {
          unsigned long long mb = __ballot(alive);
          if (!mb) break;
          int r = __builtin_ctzll(mb);
          kept |= (1ull << r);
          unsigned long long supw = __shfl(diag, r);
          alive = alive && (lane != r) && !((supw >> lane) & 1ull);
        }
        if (lane == 0) keptS[c] = kept;
      }
      __syncthreads();
      if (waveId > c && waveId < nchunk) {
        const int w = waveId;
        unsigned long long kept = keptS[c];
        unsigned long long acc = 0ull;
        if ((kept >> lane) & 1ull)
          acc = pm[(size_t)(c * 64 + lane) * NWORD + w];
        acc |= __shfl_xor(acc, 1);
        acc |= __shfl_xor(acc, 2);
        acc |= __shfl_xor(acc, 4);
        acc |= __shfl_xor(acc, 8);
        acc |= __shfl_xor(acc, 16);
        acc |= __shfl_xor(acc, 32);
        if (lane == 0) remS[w] |= acc;
      }
      __syncthreads();
    }
  }

  // ---- Phase 6: stage output (orig anchor order) + coalesced store ------
  {
    const int r = tid;
    unsigned long long kv = skey[r];
    int orig = (int)(unsigned)kv;
    bool kp = (keptS[r >> 6] >> (r & 63)) & 1ull;
    float sc = 0.0f;
    float4 bx = make_float4(0.0f, 0.0f, 0.0f, 0.0f);
    if (kp) {
      sc = -__uint_as_float(~(unsigned)(kv >> 32));  // exact original score
      bx = sbox[r];
    }
    float* oa = outAll + (size_t)orig * 5;
    oa[0] = sc; oa[1] = bx.x; oa[2] = bx.y; oa[3] = bx.z; oa[4] = bx.w;
  }
  __syncthreads();
  {
    float4* og = (float4*)(out + (size_t)p * NA * 5);
    const float4* ol = (const float4*)outAll;
    for (int t4 = tid; t4 < (NA * 5) / 4; t4 += NT) og[t4] = ol[t4];
  }
}

// ---------------------------------------------------------------------------
// Fallback: round-1 monolithic kernel (used only if ws_size is too small)
// ---------------------------------------------------------------------------
__global__ __launch_bounds__(256) void nms_mono_kernel(
    const float* __restrict__ cls_pred,
    const float* __restrict__ reg_pred,
    const float* __restrict__ anchors,
    float* __restrict__ out)
{
#pragma clang fp contract(off)
  const int bc  = blockIdx.x;
  const int b   = bc / NCLS;
  const int tid = threadIdx.x;
  const int BNT = 256, BPT = 4;

  __shared__ __align__(16) unsigned char smem[49152];
  float4*             obox  = (float4*)(smem);
  float4*             sbox  = (float4*)(smem + 16384);
  unsigned long long* skey  = (unsigned long long*)(smem + 32768);
  float*              sarea = (float*)(smem + 40960);
  int*                keepL = (int*)(smem + 45056);

  const float* regb = reg_pred + (size_t)b * 4 * NA;
  const float* scb  = cls_pred + (size_t)bc * NA;
  for (int a = tid; a < NA; a += BNT) {
    float4 an = ((const float4*)anchors)[a];
    float w  = an.z - an.x;
    float h  = an.w - an.y;
    float cx = an.x + 0.5f * w;
    float cy = an.y + 0.5f * h;
    float dx = regb[0 * NA + a] * 0.1f;
    float dy = regb[1 * NA + a] * 0.1f;
    float dw = regb[2 * NA + a] * 0.2f;
    float dh = regb[3 * NA + a] * 0.2f;
    float pcx = cx + dx * w;
    float pcy = cy + dy * h;
    float pw  = expf(dw) * w;
    float ph  = expf(dh) * h;
    float x1 = fmaxf(fmaxf(pcx - 0.5f * pw, 0.0f), 0.0f);
    float y1 = fmaxf(pcy - 0.5f * ph, 0.0f);
    float x2 = fminf(pcx + 0.5f * pw, IMG_W);
    float y2 = fminf(pcy + 0.5f * ph, IMG_H);
    obox[a] = make_float4(x1, y1, x2, y2);
    float s   = scb[a];
    float key = (s > 0.05f) ? -s : __int_as_float(0x7f800000);
    skey[a] = ((unsigned long long)enc_f32(key) << 32) | (unsigned)a;
  }
  __syncthreads();
  for (int k = 2; k <= NA; k <<= 1) {
    for (int j = k >> 1; j > 0; j >>= 1) {
      for (int m = tid; m < NA; m += BNT) {
        int mx = m ^ j;
        if (mx > m) {
          unsigned long long va = skey[m];
          unsigned long long vb = skey[mx];
          bool up = ((m & k) == 0);
          if ((va > vb) == up) { skey[m] = vb; skey[mx] = va; }
        }
      }
      __syncthreads();
    }
  }
  float4 bj[4]; float aj[4]; int kj[4];
#pragma unroll
  for (int m = 0; m < BPT; ++m) {
    int r = tid + m * BNT;
    unsigned long long kv = skey[r];
    int orig = (int)(unsigned)kv;
    float4 bx = obox[orig];
    sbox[r] = bx;
    float ar = (bx.z - bx.x) * (bx.w - bx.y);
    sarea[r] = ar;
    int kp = ((unsigned)(kv >> 32) != 0xFF800000u) ? 1 : 0;
    keepL[r] = kp;
    bj[m] = bx; aj[m] = ar; kj[m] = kp;
  }
  for (int i = 0; i < NA; ++i) {
    __syncthreads();
    if (keepL[i] == 0) continue;
    float4 bi = sbox[i];
    float  ai = sarea[i];
#pragma unroll
    for (int m = 0; m < BPT; ++m) {
      int j = tid + m * BNT;
      if (j > i && kj[m]) {
        float ix1 = fmaxf(bi.x, bj[m].x);
        float iy1 = fmaxf(bi.y, bj[m].y);
        float ix2 = fminf(bi.z, bj[m].z);
        float iy2 = fminf(bi.w, bj[m].w);
        float inter = fmaxf(ix2 - ix1, 0.0f) * fmaxf(iy2 - iy1, 0.0f);
        float un = fmaxf(ai + aj[m] - inter, 1e-9f);
        if (inter / un > 0.5f) { kj[m] = 0; keepL[j] = 0; }
      }
    }
  }
  __syncthreads();
  float4* outbox = obox;
  float*  outsc  = sarea;
#pragma unroll
  for (int m = 0; m < BPT; ++m) {
    int r = tid + m * BNT;
    unsigned long long kv = skey[r];
    int orig = (int)(unsigned)kv;
    float  sc = 0.0f;
    float4 bx = make_float4(0.0f, 0.0f, 0.0f, 0.0f);
    if (kj[m]) {
      sc = -__uint_as_float(~(unsigned)(kv >> 32));
      bx = sbox[r];
    }
    outsc[orig]  = sc;
    outbox[orig] = bx;
  }
  __syncthreads();
  float* ob = out + (size_t)bc * NA * 5;
  for (int a = tid; a < NA; a += BNT) {
    float4 bx = outbox[a];
    float* o = ob + (size_t)a * 5;
    o[0] = outsc[a]; o[1] = bx.x; o[2] = bx.y; o[3] = bx.z; o[4] = bx.w;
  }
}

// ---------------------------------------------------------------------------
extern "C" void kernel_launch(void* const* d_in, const int* in_sizes, int n_in,
                              void* d_out, int out_size, void* d_ws, size_t ws_size,
                              hipStream_t stream) {
  const float* cls = (const float*)d_in[1];
  const float* reg = (const float*)d_in[2];
  const float* anc = (const float*)d_in[3];
  float* out = (float*)d_out;

  const size_t need = (size_t)NP * NA * NWORD * 8;   // 21 MB mask matrix

  if (ws_size < need) {
    nms_mono_kernel<<<dim3(NP), dim3(256), 0, stream>>>(cls, reg, anc, out);
    return;
  }
  unsigned long long* masks = (unsigned long long*)d_ws;
  nms_fused<<<dim3(NP), dim3(NT), 0, stream>>>(cls, reg, anc, masks, out);
}